// Round 16
// baseline (365.579 us; speedup 1.0000x reference)
//
#include <hip/hip_runtime.h>

// Generalized Lotka-Volterra, RK4, D=64, batch 2048, 255 steps,
// trajectory out (batch, 256, 64) fp32 — MFMA, zero-shuffle feedback,
// CO-RESIDENT WAVES (2 per SIMD).
//
// Body = R8 verbatim (best MFMA variant, 270us): one wave / 16 batch;
// need-layout x[t][q] = X[batch p][d(t,g,q)], d = 32(t>>1)+8g+4(t&1)+q;
// E_perm rows so tile t's C-output lands exactly where the next B-fragment
// needs it; A[row=p][k=8g+j], B[k=8g+j][col=p], C[row=4g+q][col=p]
// (HW-verified R7-R15). f = x .* ((r - x) + E@x), E = A+I in f16, diagonal
// and r exact fp32. LDS-transpose coalesced store (direct stores: +64%
// WRITE_SIZE, R9).
//
// THE change (geometry only): 16 blocks x 512 threads (8 waves) instead of
// 128 blocks x 64 threads. R8 ran 1 wave/SIMD on 128 CUs — its ~1800
// enforced-wait cyc/step were architecturally unfillable (no co-resident
// wave to issue during stalls; R11 showed intra-wave ILP can't fill them
// because per-wave wait states block the wave's entire issue stream).
// 8 waves/block -> 2 waves/SIMD: wave B issues during wave A's waits.
// Issue budget ~560 VALU-cyc/step/wave -> wall/step ~max(2x560, chain)
// ~1200-1500 cyc -> 130-165us predicted. Waves are independent (no
// __syncthreads); each has a private LDS slice.

constexpr int D   = 64;   // state dimension
constexpr int NT  = 256;  // trajectory length (255 RK4 steps)
constexpr int BW  = 16;   // batch elements per wave (MFMA N)
constexpr int WPW = 8;    // waves per block -> 2 per SIMD

typedef _Float16 f16x8 __attribute__((ext_vector_type(8)));
typedef float    f32x4 __attribute__((ext_vector_type(4)));

__device__ __forceinline__ uint32_t pkrtz(float lo, float hi) {
    return __builtin_bit_cast(uint32_t, __builtin_amdgcn_cvt_pkrtz(lo, hi));
}
__device__ __forceinline__ f32x4 vsplat(float v) {
    return (f32x4){v, v, v, v};
}

// f(XT) = XT .* ((r - XT) + E@XT); XT, F are f32x4[4] in the need-layout.
#define FEVAL(XT, F)                                                          \
    do {                                                                      \
        union { uint32_t u[4]; f16x8 v; } u0_, u1_;                           \
        u0_.u[0] = pkrtz(XT[0][0], XT[0][1]);                                 \
        u0_.u[1] = pkrtz(XT[0][2], XT[0][3]);                                 \
        u0_.u[2] = pkrtz(XT[1][0], XT[1][1]);                                 \
        u0_.u[3] = pkrtz(XT[1][2], XT[1][3]);                                 \
        u1_.u[0] = pkrtz(XT[2][0], XT[2][1]);                                 \
        u1_.u[1] = pkrtz(XT[2][2], XT[2][3]);                                 \
        u1_.u[2] = pkrtz(XT[3][0], XT[3][1]);                                 \
        u1_.u[3] = pkrtz(XT[3][2], XT[3][3]);                                 \
        const f16x8 bf0 = u0_.v, bf1 = u1_.v;                                 \
        _Pragma("unroll")                                                     \
        for (int t_ = 0; t_ < 4; ++t_) {                                      \
            f32x4 c_ = rl[t_] - XT[t_];                                       \
            c_ = __builtin_amdgcn_mfma_f32_16x16x32_f16(af[t_][0], bf0, c_, 0, 0, 0); \
            c_ = __builtin_amdgcn_mfma_f32_16x16x32_f16(af[t_][1], bf1, c_, 0, 0, 0); \
            F[t_] = XT[t_] * c_;                                              \
        }                                                                     \
    } while (0)

// Coalesce step TS through this wave's LDS slice (pad-17 rows, 2-way banks).
#define STORE_STEP(TS)                                                        \
    do {                                                                      \
        _Pragma("unroll")                                                     \
        for (int t_ = 0; t_ < 4; ++t_)                                        \
            _Pragma("unroll")                                                 \
            for (int q_ = 0; q_ < 4; ++q_)                                    \
                xT[(dbase[t_] + q_) * 17 + p] = x[t_][q_];                    \
        asm volatile("s_waitcnt lgkmcnt(0)" ::: "memory");                    \
        _Pragma("unroll")                                                     \
        for (int i_ = 0; i_ < 16; ++i_)                                       \
            outp[(size_t)i_ * NT * D + (size_t)(TS) * D + lane] =             \
                xT[lane * 17 + i_];                                           \
    } while (0)

__global__ __launch_bounds__(WPW * 64)
void glv_rk4_mfma(const float* __restrict__ x0,
                  const float* __restrict__ r,
                  const float* __restrict__ A,
                  const float* __restrict__ tgrid,
                  float* __restrict__ out)
{
    const int lane = threadIdx.x & 63;
    const int wid  = threadIdx.x >> 6;
    const int g    = lane >> 4;
    const int p    = lane & 15;
    const int b0   = (blockIdx.x * WPW + wid) * BW;  // this wave's batch base

    __shared__ float xTs[WPW][D * 17];         // per-wave store staging
    float* const xT = &xTs[wid][0];

    int dbase[4];
#pragma unroll
    for (int t = 0; t < 4; ++t) dbase[t] = 32 * (t >> 1) + 8 * g + 4 * (t & 1);

    // Stationary A-fragments of permuted E (E = A + I) — HW-verified layout.
    f16x8 af[4][2];
#pragma unroll
    for (int t = 0; t < 4; ++t) {
        const int rE = 32 * (t >> 1) + 8 * (p >> 2) + 4 * (t & 1) + (p & 3);
#pragma unroll
        for (int kh = 0; kh < 2; ++kh) {
            const int c0 = 32 * kh + 8 * g;
            const float4 v0 = *reinterpret_cast<const float4*>(A + rE * D + c0);
            const float4 v1 = *reinterpret_cast<const float4*>(A + rE * D + c0 + 4);
            float e[8] = {v0.x, v0.y, v0.z, v0.w, v1.x, v1.y, v1.z, v1.w};
#pragma unroll
            for (int j = 0; j < 8; ++j)
                if (rE == c0 + j) e[j] += 1.0f;
            union { uint32_t u[4]; f16x8 v; } un;
            un.u[0] = pkrtz(e[0], e[1]);
            un.u[1] = pkrtz(e[2], e[3]);
            un.u[2] = pkrtz(e[4], e[5]);
            un.u[3] = pkrtz(e[6], e[7]);
            af[t][kh] = un.v;
        }
    }
    // "+v" pins: keep af loop-resident in arch VGPRs (R10: "+a" regressed).
#pragma unroll
    for (int t = 0; t < 4; ++t)
#pragma unroll
        for (int kh = 0; kh < 2; ++kh)
            asm volatile("" : "+v"(af[t][kh]));

    // r and x0 in the need-layout (dbase is a multiple of 4 -> f32x4 loads).
    f32x4 rl[4], x[4];
#pragma unroll
    for (int t = 0; t < 4; ++t) {
        rl[t] = *reinterpret_cast<const f32x4*>(r + dbase[t]);
        x[t]  = *reinterpret_cast<const f32x4*>(x0 + (b0 + p) * D + dbase[t]);
    }

    const float dt = tgrid[1] - tgrid[0];
    const float h2 = 0.5f * dt;
    const float h6 = dt * (1.0f / 6.0f);
    float* const outp = out + (size_t)b0 * NT * D;

    STORE_STEP(0);                             // t = 0 output is x0

    f32x4 s[4], xst[4], k[4];

    for (int ts = 1; ts < NT; ++ts) {
        FEVAL(x, k);                                   // k1
#pragma unroll
        for (int t = 0; t < 4; ++t) {
            s[t]   = x[t] + vsplat(h6) * k[t];
            xst[t] = x[t] + vsplat(h2) * k[t];
        }
        FEVAL(xst, k);                                 // k2
#pragma unroll
        for (int t = 0; t < 4; ++t) {
            s[t]   = s[t] + vsplat(2.0f * h6) * k[t];
            xst[t] = x[t] + vsplat(h2) * k[t];
        }
        FEVAL(xst, k);                                 // k3
#pragma unroll
        for (int t = 0; t < 4; ++t) {
            s[t]   = s[t] + vsplat(2.0f * h6) * k[t];
            xst[t] = x[t] + vsplat(dt) * k[t];
        }
        FEVAL(xst, k);                                 // k4
#pragma unroll
        for (int t = 0; t < 4; ++t)
            x[t] = s[t] + vsplat(h6) * k[t];

        STORE_STEP(ts);
    }
}

extern "C" void kernel_launch(void* const* d_in, const int* in_sizes, int n_in,
                              void* d_out, int out_size, void* d_ws, size_t ws_size,
                              hipStream_t stream) {
    const float* x0    = (const float*)d_in[0];
    const float* r     = (const float*)d_in[1];
    const float* A     = (const float*)d_in[2];
    const float* tgrid = (const float*)d_in[3];
    float* out         = (float*)d_out;

    const int batch = in_sizes[0] / D;          // 2048
    dim3 grid(batch / (BW * WPW));              // 16 blocks
    dim3 block(WPW * 64);                       // 512 threads = 8 waves

    glv_rk4_mfma<<<grid, block, 0, stream>>>(x0, r, A, tgrid, out);
}

// Round 17
// 281.133 us; speedup vs baseline: 1.3004x; 1.3004x over previous
//
#include <hip/hip_runtime.h>

// Generalized Lotka-Volterra, RK4, D=64, batch 2048, 255 steps,
// trajectory out (batch, 256, 64) fp32.
//
// 2048-wave family (2 waves/SIMD on all 256 CUs), SPLIT-ROW dot product:
//
//   R12 (249us) is LDS-return-bound: every lane reads the full 64-comp f16
//   vector = 8KB/feval/wave. This round pairs lanes (i, i+32):
//     lane i<32 : reads x-pairs [0:16)  (dwords 0-15),  dots LOW halves of
//                 rows i and i+32  -> partials accA(row i), accB(row i+32)
//     lane i>=32: reads x-pairs [16:32) (dwords 16-31), dots HIGH halves of
//                 the same rows    -> partials accA, accB
//   4 ds_read_b128 per feval = 4KB/feval/wave (HALF of R12). Combine with
//   ONE v_permlane32_swap_b32 on the partials (not 16 operand-swaps = R13's
//   mistake): m = own needed partial, n = partner's needed partial,
//   total = m + partnerswap(n). Swap convention probed once at startup.
//
//   LDS floor: 2.09M fevals x 4KB / 68.8 TB/s ~= 124us. VALU ~47 instr
//   ~94 cyc/feval -> ~80us. Predicted 150-185us, LDS-bound.
//
// Phantom-AGPR fix (R14-verified recipe, VGPR 36->88): waves_per_eu(2,2)
// pins the occupancy target at the structural 2/SIMD; per-iteration "+v"
// pins make AGPR-homing of e[] cost 64 copies/iter -> VGPR residency wins.
//
// Numerics: same family as R5/R6/R12 (E = A + I in f16 pairs, diagonal -x
// and growth r exact fp32) — passing at absmax 3.9e-3.

constexpr int D   = 64;   // state dimension == wavefront size
constexpr int NT  = 256;  // trajectory length (255 RK4 steps)
constexpr int WPB = 4;    // waves (= batch elements) per block

typedef unsigned u32x2 __attribute__((ext_vector_type(2)));

__device__ __forceinline__ uint32_t pkrtz(float lo, float hi) {
    return __builtin_bit_cast(uint32_t, __builtin_amdgcn_cvt_pkrtz(lo, hi));
}
// DPP xor-1 on a float (quad_perm [1,0,3,2]).
__device__ __forceinline__ float dpp_xor1(float v) {
    return __int_as_float(__builtin_amdgcn_update_dpp(
        0, __float_as_int(v), 0xB1, 0xF, 0xF, true));
}
// acc += dot2(e_pair, x_pair), both operands VGPR.
__device__ __forceinline__ float dot2v(float acc, uint32_t e, uint32_t x) {
    asm("v_dot2_f32_f16 %0, %1, %2, %0" : "+v"(acc) : "v"(e), "v"(x));
    return acc;
}
__device__ __forceinline__ u32x2 plswap(uint32_t v) {
    return __builtin_amdgcn_permlane32_swap(v, v, false, false);
}

// f(xt) = xt * (r - xt + E@xt); split-row dot + single partial-swap combine.
#define FEVAL(XT, RES)                                                        \
    do {                                                                      \
        const float xt_ = (XT);                                               \
        const uint32_t pair_ = pkrtz(xt_, dpp_xor1(xt_)); /* even lanes */    \
        wbuf[waddr] = pair_;                              /* 1 ds_write */    \
        asm volatile("s_waitcnt lgkmcnt(0)" ::: "memory");                    \
        float aA0 = 0.f, aA1 = 0.f, aA2 = 0.f, aA3 = 0.f;                     \
        float aB0 = 0.f, aB1 = 0.f, aB2 = 0.f, aB3 = 0.f;                     \
        _Pragma("unroll")                                                     \
        for (int j = 0; j < 4; ++j) {               /* 4 half-split b128 */   \
            const uint4 v_ = *reinterpret_cast<const uint4*>(rbuf + 4 * j);   \
            aA0 = dot2v(aA0, ea[4 * j + 0], v_.x);                            \
            aB0 = dot2v(aB0, eb[4 * j + 0], v_.x);                            \
            aA1 = dot2v(aA1, ea[4 * j + 1], v_.y);                            \
            aB1 = dot2v(aB1, eb[4 * j + 1], v_.y);                            \
            aA2 = dot2v(aA2, ea[4 * j + 2], v_.z);                            \
            aB2 = dot2v(aB2, eb[4 * j + 2], v_.z);                            \
            aA3 = dot2v(aA3, ea[4 * j + 3], v_.w);                            \
            aB3 = dot2v(aB3, eb[4 * j + 3], v_.w);                            \
        }                                                                     \
        const float accA_ = (aA0 + aA1) + (aA2 + aA3);                        \
        const float accB_ = (aB0 + aB1) + (aB2 + aB3);                        \
        const float m_ = isLow ? accA_ : accB_;   /* own needed partial   */  \
        const float n_ = isLow ? accB_ : accA_;   /* partner's needed one */  \
        const u32x2 sw_ = plswap(__builtin_bit_cast(uint32_t, n_));           \
        const float pn_ = __builtin_bit_cast(                                 \
            float, xIsPartner ? sw_.x : sw_.y);                               \
        const float tot_ = m_ + pn_;                                          \
        RES = xt_ * ((ri + tot_) - xt_);                                      \
    } while (0)

// Per-iteration residency pin (R14-verified): e[] stays in arch VGPRs.
#define PIN8(ARR, B)                                                          \
    asm volatile("" : "+v"(ARR[B + 0]), "+v"(ARR[B + 1]), "+v"(ARR[B + 2]),   \
                      "+v"(ARR[B + 3]), "+v"(ARR[B + 4]), "+v"(ARR[B + 5]),   \
                      "+v"(ARR[B + 6]), "+v"(ARR[B + 7]))

__global__ __launch_bounds__(WPB * 64)
__attribute__((amdgpu_waves_per_eu(2, 2)))
void glv_rk4_kernel(const float* __restrict__ x0,
                    const float* __restrict__ r,
                    const float* __restrict__ A,
                    const float* __restrict__ tgrid,
                    float* __restrict__ out)
{
    const int lane = threadIdx.x & 63;
    const int wid  = threadIdx.x >> 6;
    const int b    = blockIdx.x * WPB + wid;   // batch element for this wave
    const bool isLow = (lane < 32);

    // Per-wave broadcast buffer: pairs 0-31 at dwords 0-31, shadow 32-63.
    __shared__ uint32_t xf16[WPB][64];
    uint32_t* const wbuf = &xf16[wid][0];
    const int waddr = (lane >> 1) + (lane & 1) * 32;  // shadow for odd lanes
    uint32_t* const rbuf = wbuf + (isLow ? 0 : 16);   // own half's pairs

    // Probe permlane32_swap convention once: which component carries the
    // partner (lane^32) value. Wave-uniform.
    const u32x2 pr = plswap((uint32_t)lane);
    const bool xIsPartner =
        (__builtin_amdgcn_readfirstlane((int)pr.x) == 32);

    // Two half-rows of E = A + I, packed f16 pairs -> 32 VGPRs.
    // rowA = lane&31 (low), rowB = rowA+32; column half = own lane half.
    const int rowA = lane & 31;
    const int rowB = rowA + 32;
    const int cb   = isLow ? 0 : 32;           // column base
    uint32_t ea[16], eb[16];
#pragma unroll
    for (int J = 0; J < 16; J += 2) {
        const float4 va = *reinterpret_cast<const float4*>(A + rowA * D + cb + 2 * J);
        const float4 vb = *reinterpret_cast<const float4*>(A + rowB * D + cb + 2 * J);
        float a0 = va.x, a1 = va.y, a2 = va.z, a3 = va.w;
        float b0 = vb.x, b1 = vb.y, b2 = vb.z, b3 = vb.w;
        if (rowA == cb + 2 * J)     a0 += 1.0f;
        if (rowA == cb + 2 * J + 1) a1 += 1.0f;
        if (rowA == cb + 2 * J + 2) a2 += 1.0f;
        if (rowA == cb + 2 * J + 3) a3 += 1.0f;
        if (rowB == cb + 2 * J)     b0 += 1.0f;
        if (rowB == cb + 2 * J + 1) b1 += 1.0f;
        if (rowB == cb + 2 * J + 2) b2 += 1.0f;
        if (rowB == cb + 2 * J + 3) b3 += 1.0f;
        ea[J]     = pkrtz(a0, a1);
        ea[J + 1] = pkrtz(a2, a3);
        eb[J]     = pkrtz(b0, b1);
        eb[J + 1] = pkrtz(b2, b3);
    }

    const float ri = r[lane];
    const float dt = tgrid[1] - tgrid[0];
    const float h2 = 0.5f * dt;
    const float h6 = dt * (1.0f / 6.0f);

    float x = x0[(size_t)b * D + lane];

    float* o = out + (size_t)b * NT * D + lane;
    *o = x; o += D;                            // t = 0 is x0

    for (int t = 1; t < NT; ++t) {
        PIN8(ea, 0); PIN8(ea, 8); PIN8(eb, 0); PIN8(eb, 8);
        float k1, k2, k3, k4;
        FEVAL(x, k1);
        FEVAL(fmaf(h2, k1, x), k2);
        FEVAL(fmaf(h2, k2, x), k3);
        FEVAL(fmaf(dt, k3, x), k4);
        x = fmaf(h6, (k1 + k4) + 2.0f * (k2 + k3), x);
        *o = x; o += D;                        // coalesced 256 B/wave store
    }
}

extern "C" void kernel_launch(void* const* d_in, const int* in_sizes, int n_in,
                              void* d_out, int out_size, void* d_ws, size_t ws_size,
                              hipStream_t stream) {
    const float* x0    = (const float*)d_in[0];
    const float* r     = (const float*)d_in[1];
    const float* A     = (const float*)d_in[2];
    const float* tgrid = (const float*)d_in[3];
    float* out         = (float*)d_out;

    const int batch = in_sizes[0] / D;          // 2048
    dim3 grid(batch / WPB);                     // 512 blocks
    dim3 block(WPB * 64);                       // 256 threads = 4 waves

    glv_rk4_kernel<<<grid, block, 0, stream>>>(x0, r, A, tgrid, out);
}

// Round 18
// 248.977 us; speedup vs baseline: 1.4683x; 1.1292x over previous
//
#include <hip/hip_runtime.h>

// Generalized Lotka-Volterra, RK4, D=64, batch 2048, 255 steps,
// trajectory out (batch, 256, 64) fp32.
//
// FINAL (= round-12 kernel verbatim; best measured, 249us, sitting ~2.5%
// above its structural floor). Closure argument from the 17-round search:
//
//   MAC floor:      64 rows x 64 MACs / 64 lanes = 32 v_dot2 per lane per
//                   feval — invariant under any lane-split (R17 proved).
//   Delivery floor: each lane needs all 64 f16 comps = 128 B/lane/feval.
//                   This kernel reads exactly that (8 uniform ds_read_b128).
//                   LDS-return floor = 2.09M fevals x 8KB / 68.8 TB/s
//                   ~= 243us; measured 249us. Binder = LDS return BW.
//   Alternatives all measured worse: readlane bcast (R14: 324us, ~8cyc/op),
//   permlane hybrid (R17: 313us), ds_swizzle (R3: 515us), f32 LDS (R4:
//   477us, 2x bytes), MFMA hw-broadcast (R8: 270us — capped at 128 waves,
//   co-residency null R16), independent-chain ILP (R11: null).
//
// Structure: one wave per batch element (2048 waves = 2/SIMD on 256 CUs).
// E = A + I packed f16 pairs in VGPRs; f = x .* ((r - x) + E@x): diagonal
// and growth exact fp32, only the small coupling term in f16 (absmax
// 3.9e-3 vs 2e-2 threshold). Broadcast: pack (x_2j, x_2j+1) via DPP-xor1 +
// v_cvt_pkrtz, one ds_write_b32/lane (odd lanes -> never-read shadow slot),
// 8 uniform-address ds_read_b128 (hardware broadcast, conflict-free),
// 32 v_dot2_f32_f16 with VGPR operands. DS in-order per wave -> lgkmcnt(0)
// is the only sync; no barriers anywhere.

constexpr int D   = 64;   // state dimension == wavefront size
constexpr int NT  = 256;  // trajectory length (255 RK4 steps)
constexpr int WPB = 4;    // waves (= batch elements) per block

__device__ __forceinline__ uint32_t pkrtz(float lo, float hi) {
    return __builtin_bit_cast(uint32_t, __builtin_amdgcn_cvt_pkrtz(lo, hi));
}
// DPP xor-1 on a float (quad_perm [1,0,3,2]).
__device__ __forceinline__ float dpp_xor1(float v) {
    return __int_as_float(__builtin_amdgcn_update_dpp(
        0, __float_as_int(v), 0xB1, 0xF, 0xF, true));
}
// acc += dot2(e_pair, x_pair), both operands VGPR.
__device__ __forceinline__ float dot2v(float acc, uint32_t e, uint32_t x) {
    asm("v_dot2_f32_f16 %0, %1, %2, %0" : "+v"(acc) : "v"(e), "v"(x));
    return acc;
}

// f(xt) = xt * (r - xt + E@xt); broadcast via f16-packed LDS.
#define FEVAL(XT, RES)                                                        \
    do {                                                                      \
        const float xt_ = (XT);                                               \
        const uint32_t pair_ = pkrtz(xt_, dpp_xor1(xt_)); /* even lanes */    \
        wbuf[waddr] = pair_;                              /* 1 ds_write */    \
        asm volatile("s_waitcnt lgkmcnt(0)" ::: "memory");                    \
        float a0 = ri, a1 = 0.f, a2 = 0.f, a3 = 0.f;                          \
        _Pragma("unroll")                                                     \
        for (int J = 0; J < 8; ++J) {                     /* 8 uniform b128 */\
            const uint4 v_ = *reinterpret_cast<const uint4*>(wbuf + 4 * J);   \
            a0 = dot2v(a0, e[4 * J + 0], v_.x);                               \
            a1 = dot2v(a1, e[4 * J + 1], v_.y);                               \
            a2 = dot2v(a2, e[4 * J + 2], v_.z);                               \
            a3 = dot2v(a3, e[4 * J + 3], v_.w);                               \
        }                                                                     \
        RES = xt_ * (((a0 + a1) + (a2 + a3)) - xt_);                          \
    } while (0)

__global__ __launch_bounds__(WPB * 64, 2)
void glv_rk4_kernel(const float* __restrict__ x0,
                    const float* __restrict__ r,
                    const float* __restrict__ A,
                    const float* __restrict__ tgrid,
                    float* __restrict__ out)
{
    const int lane = threadIdx.x & 63;
    const int wid  = threadIdx.x >> 6;
    const int b    = blockIdx.x * WPB + wid;   // batch element for this wave

    // Per-wave broadcast buffer: 32 real pair-slots + 32 shadow (odd lanes).
    __shared__ uint32_t xf16[WPB][64];
    uint32_t* const wbuf = &xf16[wid][0];
    const int waddr = (lane >> 1) + (lane & 1) * 32;  // shadow for odd lanes

    // E = A + I, row `lane`, packed f16 pairs -> 32 VGPRs (one-time setup).
    uint32_t e[D / 2];
#pragma unroll
    for (int J = 0; J < D / 2; J += 2) {
        const float4 v = *reinterpret_cast<const float4*>(A + lane * D + 2 * J);
        const float e0 = v.x + ((2 * J)     == lane ? 1.0f : 0.0f);
        const float e1 = v.y + ((2 * J + 1) == lane ? 1.0f : 0.0f);
        const float e2 = v.z + ((2 * J + 2) == lane ? 1.0f : 0.0f);
        const float e3 = v.w + ((2 * J + 3) == lane ? 1.0f : 0.0f);
        e[J]     = pkrtz(e0, e1);
        e[J + 1] = pkrtz(e2, e3);
    }
    // Anti-sink fence: E loads execute exactly once, before the loop.
#pragma unroll
    for (int J = 0; J < D / 2; ++J)
        asm volatile("" : "+v"(e[J]));

    const float ri = r[lane];
    const float dt = tgrid[1] - tgrid[0];
    const float h2 = 0.5f * dt;
    const float h6 = dt * (1.0f / 6.0f);

    float x = x0[(size_t)b * D + lane];

    float* o = out + (size_t)b * NT * D + lane;
    *o = x; o += D;                            // t = 0 is x0

    for (int t = 1; t < NT; ++t) {
        float k1, k2, k3, k4;
        FEVAL(x, k1);
        FEVAL(fmaf(h2, k1, x), k2);
        FEVAL(fmaf(h2, k2, x), k3);
        FEVAL(fmaf(dt, k3, x), k4);
        x = fmaf(h6, (k1 + k4) + 2.0f * (k2 + k3), x);
        *o = x; o += D;                        // coalesced 256 B/wave store
    }
}

extern "C" void kernel_launch(void* const* d_in, const int* in_sizes, int n_in,
                              void* d_out, int out_size, void* d_ws, size_t ws_size,
                              hipStream_t stream) {
    const float* x0    = (const float*)d_in[0];
    const float* r     = (const float*)d_in[1];
    const float* A     = (const float*)d_in[2];
    const float* tgrid = (const float*)d_in[3];
    float* out         = (float*)d_out;

    const int batch = in_sizes[0] / D;          // 2048
    dim3 grid(batch / WPB);                     // 512 blocks
    dim3 block(WPB * 64);                       // 256 threads = 4 waves

    glv_rk4_kernel<<<grid, block, 0, stream>>>(x0, r, A, tgrid, out);
}

// Round 19
// 186.501 us; speedup vs baseline: 1.9602x; 1.3350x over previous
//
#include <hip/hip_runtime.h>

// Generalized Lotka-Volterra, RK4, D=64, batch 2048, 255 steps,
// trajectory out (batch, 256, 64) fp32.
//
// R12 (249us) sits on the f16 LDS-return floor: 128 B/lane/feval delivered
// by 8 uniform ds_read_b128. The only lever that moves THAT floor is fewer
// delivered bytes -> i8. This round:
//   - x broadcast as i8: q = round(127*x) (x in (0,1] by gLV dynamics),
//     4 lanes' bytes merged per dword via 2x (DPP-xor + lshl_or), one
//     ds_write_b32/lane (lanes !=0 mod 4 hit never-read shadow slots),
//     FOUR uniform ds_read_b128 = 64 B/lane/feval (half of R12).
//   - E = A + I quantized i8 with PER-ROW scale sE = rowmax/127 (~6e-5
//     abs err/elem); 16 v_dot4_i32_i8 (4 MACs each), int32 accumulate,
//     one cvt + scale at the end: E@x = idot * (rowmax/127^2).
//   - diagonal -x and growth r remain exact fp32: f = x*((r - x) + E@x).
// Error budget: i8-E ~6e-4 + i8-x ~6e-4 per feval in the coupling term
// -> ~2-3e-3 added trajectory error; on top of the f16-family 3.9e-3 ->
// ~7e-3 predicted absmax vs 2e-2 threshold.
//
// Phantom-AGPR insurance (R14-verified): waves_per_eu(2,2) pins the
// occupancy target at the structural 2/SIMD; per-iteration "+v" pins keep
// eq[] in arch VGPRs. DS in-order per wave -> lgkmcnt(0) only, no barriers.
// Fallback if this regresses/fails accuracy: R12/R18 (249us) is final.

constexpr int D   = 64;   // state dimension == wavefront size
constexpr int NT  = 256;  // trajectory length (255 RK4 steps)
constexpr int WPB = 4;    // waves (= batch elements) per block

__device__ __forceinline__ uint32_t dpp_xor1_u(uint32_t v) {   // quad_perm [1,0,3,2]
    return (uint32_t)__builtin_amdgcn_update_dpp(0, (int)v, 0xB1, 0xF, 0xF, true);
}
__device__ __forceinline__ uint32_t dpp_xor2_u(uint32_t v) {   // quad_perm [2,3,0,1]
    return (uint32_t)__builtin_amdgcn_update_dpp(0, (int)v, 0x4E, 0xF, 0xF, true);
}
// acc += dot4(i8x4, i8x4) — signed 8-bit dot product, int32 accumulate.
__device__ __forceinline__ int dot4(int acc, uint32_t e, uint32_t x) {
#if __has_builtin(__builtin_amdgcn_sdot4)
    return __builtin_amdgcn_sdot4((int)e, (int)x, acc, false);
#else
    asm("v_dot4_i32_i8 %0, %1, %2, %0" : "+v"(acc) : "v"(e), "v"(x));
    return acc;
#endif
}

// f(xt) = xt * (r - xt + E@xt); broadcast via i8-packed LDS.
#define FEVAL(XT, RES)                                                        \
    do {                                                                      \
        const float xt_ = (XT);                                               \
        const uint32_t q_  = (uint32_t)fmaf(xt_, 127.0f, 0.5f);               \
        const uint32_t t1_ = q_  | (dpp_xor1_u(q_)  << 8);                    \
        const uint32_t t2_ = t1_ | (dpp_xor2_u(t1_) << 16);                   \
        wbuf[waddr] = t2_;                                /* 1 ds_write */    \
        asm volatile("s_waitcnt lgkmcnt(0)" ::: "memory");                    \
        int a0 = 0, a1 = 0, a2 = 0, a3 = 0;                                   \
        _Pragma("unroll")                                                     \
        for (int J = 0; J < 4; ++J) {                     /* 4 uniform b128 */\
            const uint4 v_ = *reinterpret_cast<const uint4*>(wbuf + 4 * J);   \
            a0 = dot4(a0, eq[4 * J + 0], v_.x);                               \
            a1 = dot4(a1, eq[4 * J + 1], v_.y);                               \
            a2 = dot4(a2, eq[4 * J + 2], v_.z);                               \
            a3 = dot4(a3, eq[4 * J + 3], v_.w);                               \
        }                                                                     \
        const float cp_ = (float)((a0 + a1) + (a2 + a3)) * scl;               \
        RES = xt_ * ((ri + cp_) - xt_);                                       \
    } while (0)

// Per-iteration residency pin (R14-verified recipe).
#define PIN8(B)                                                               \
    asm volatile("" : "+v"(eq[B + 0]), "+v"(eq[B + 1]), "+v"(eq[B + 2]),      \
                      "+v"(eq[B + 3]), "+v"(eq[B + 4]), "+v"(eq[B + 5]),      \
                      "+v"(eq[B + 6]), "+v"(eq[B + 7]))

__global__ __launch_bounds__(WPB * 64)
__attribute__((amdgpu_waves_per_eu(2, 2)))
void glv_rk4_kernel(const float* __restrict__ x0,
                    const float* __restrict__ r,
                    const float* __restrict__ A,
                    const float* __restrict__ tgrid,
                    float* __restrict__ out)
{
    const int lane = threadIdx.x & 63;
    const int wid  = threadIdx.x >> 6;
    const int b    = blockIdx.x * WPB + wid;   // batch element for this wave

    // Per-wave broadcast buffer: 16 real dwords (64 x i8) + 48 shadow.
    __shared__ uint32_t xq[WPB][64];
    uint32_t* const wbuf = &xq[wid][0];
    const int waddr = (lane >> 2) + (lane & 3) * 16;  // shadow for lane%4 != 0

    // E = A + I, row `lane`, quantized i8 with per-row scale -> 16 VGPRs.
    float ev[D];
    float rowmax = 1e-30f;
#pragma unroll
    for (int j = 0; j < D; j += 4) {
        const float4 v = *reinterpret_cast<const float4*>(A + lane * D + j);
        ev[j + 0] = v.x + ((j + 0) == lane ? 1.0f : 0.0f);
        ev[j + 1] = v.y + ((j + 1) == lane ? 1.0f : 0.0f);
        ev[j + 2] = v.z + ((j + 2) == lane ? 1.0f : 0.0f);
        ev[j + 3] = v.w + ((j + 3) == lane ? 1.0f : 0.0f);
        rowmax = fmaxf(rowmax, fmaxf(fmaxf(fabsf(ev[j]), fabsf(ev[j + 1])),
                                     fmaxf(fabsf(ev[j + 2]), fabsf(ev[j + 3]))));
    }
    const float qinv = 127.0f / rowmax;
    const float scl  = rowmax * (1.0f / (127.0f * 127.0f));

    uint32_t eq[D / 4];
#pragma unroll
    for (int J = 0; J < D / 4; ++J) {
        const int b0 = (int)rintf(ev[4 * J + 0] * qinv);
        const int b1 = (int)rintf(ev[4 * J + 1] * qinv);
        const int b2 = (int)rintf(ev[4 * J + 2] * qinv);
        const int b3 = (int)rintf(ev[4 * J + 3] * qinv);
        eq[J] = (uint32_t)(b0 & 0xFF) | ((uint32_t)(b1 & 0xFF) << 8) |
                ((uint32_t)(b2 & 0xFF) << 16) | ((uint32_t)(b3 & 0xFF) << 24);
    }

    const float ri = r[lane];
    const float dt = tgrid[1] - tgrid[0];
    const float h2 = 0.5f * dt;
    const float h6 = dt * (1.0f / 6.0f);

    float x = x0[(size_t)b * D + lane];

    float* o = out + (size_t)b * NT * D + lane;
    *o = x; o += D;                            // t = 0 is x0

    for (int t = 1; t < NT; ++t) {
        PIN8(0); PIN8(8);                      // keep eq in arch VGPRs
        float k1, k2, k3, k4;
        FEVAL(x, k1);
        FEVAL(fmaf(h2, k1, x), k2);
        FEVAL(fmaf(h2, k2, x), k3);
        FEVAL(fmaf(dt, k3, x), k4);
        x = fmaf(h6, (k1 + k4) + 2.0f * (k2 + k3), x);
        *o = x; o += D;                        // coalesced 256 B/wave store
    }
}

extern "C" void kernel_launch(void* const* d_in, const int* in_sizes, int n_in,
                              void* d_out, int out_size, void* d_ws, size_t ws_size,
                              hipStream_t stream) {
    const float* x0    = (const float*)d_in[0];
    const float* r     = (const float*)d_in[1];
    const float* A     = (const float*)d_in[2];
    const float* tgrid = (const float*)d_in[3];
    float* out         = (float*)d_out;

    const int batch = in_sizes[0] / D;          // 2048
    dim3 grid(batch / WPB);                     // 512 blocks
    dim3 block(WPB * 64);                       // 256 threads = 4 waves

    glv_rk4_kernel<<<grid, block, 0, stream>>>(x0, r, A, tgrid, out);
}

// Round 20
// 169.115 us; speedup vs baseline: 2.1617x; 1.1028x over previous
//
#include <hip/hip_runtime.h>

// Generalized Lotka-Volterra, RK4, D=64, batch 2048, 255 steps,
// trajectory out (batch, 256, 64) fp32.
//
// = Round-19 i8 kernel (186us, absmax 3.9e-3) with ONE change: the
// per-feval `s_waitcnt lgkmcnt(0)` hardware drain between ds_write and the
// uniform ds_reads is replaced by a zero-instruction compile-order barrier.
// Rationale: the DS pipeline processes a wave's LDS ops IN ISSUE ORDER
// (per-wave FIFO) — a read issued after a write observes the written data;
// lgkmcnt only gates register return, which the compiler already inserts
// per-read (fine-grained lgkmcnt(3/2/1/0)). The explicit drain serialized
// write-latency into every feval's critical chain (x4 per step) and its
// "memory" clobber blocked dot4/read overlap. If same-wave DS in-order
// does NOT hold on gfx950, this races and absmax explodes -> revert R19.
//
// Everything else identical to R19:
//   - x broadcast as i8 (q = round(127*x), x in (0,1]): 2x DPP + lshl_or
//     merges 4 lanes' bytes per dword, 1 ds_write_b32/lane (shadow slots
//     for lane%4 != 0), FOUR uniform ds_read_b128 = 64 B/lane/feval.
//   - E = A + I quantized i8 per-row (sE = rowmax/127); 16 v_dot4_i32_i8,
//     int32 accumulate, one scale at the end. Diagonal -x and r exact fp32.
//   - waves_per_eu(2,2) + per-iteration pins (R14 recipe) keep eq[] in
//     arch VGPRs (VGPR_Count 88 confirmed in R19).

constexpr int D   = 64;   // state dimension == wavefront size
constexpr int NT  = 256;  // trajectory length (255 RK4 steps)
constexpr int WPB = 4;    // waves (= batch elements) per block

__device__ __forceinline__ uint32_t dpp_xor1_u(uint32_t v) {   // quad_perm [1,0,3,2]
    return (uint32_t)__builtin_amdgcn_update_dpp(0, (int)v, 0xB1, 0xF, 0xF, true);
}
__device__ __forceinline__ uint32_t dpp_xor2_u(uint32_t v) {   // quad_perm [2,3,0,1]
    return (uint32_t)__builtin_amdgcn_update_dpp(0, (int)v, 0x4E, 0xF, 0xF, true);
}
// acc += dot4(i8x4, i8x4) — signed 8-bit dot product, int32 accumulate.
__device__ __forceinline__ int dot4(int acc, uint32_t e, uint32_t x) {
#if __has_builtin(__builtin_amdgcn_sdot4)
    return __builtin_amdgcn_sdot4((int)e, (int)x, acc, false);
#else
    asm("v_dot4_i32_i8 %0, %1, %2, %0" : "+v"(acc) : "v"(e), "v"(x));
    return acc;
#endif
}

// f(xt) = xt * (r - xt + E@xt); broadcast via i8-packed LDS.
// Compile-order barrier only between write and reads: the per-wave DS FIFO
// guarantees the reads observe the write; compiler inserts minimal lgkmcnt
// for the read RETURNS right before each consuming dot4.
#define FEVAL(XT, RES)                                                        \
    do {                                                                      \
        const float xt_ = (XT);                                               \
        const uint32_t q_  = (uint32_t)fmaf(xt_, 127.0f, 0.5f);               \
        const uint32_t t1_ = q_  | (dpp_xor1_u(q_)  << 8);                    \
        const uint32_t t2_ = t1_ | (dpp_xor2_u(t1_) << 16);                   \
        wbuf[waddr] = t2_;                                /* 1 ds_write */    \
        asm volatile("" ::: "memory");                    /* order only  */   \
        int a0 = 0, a1 = 0, a2 = 0, a3 = 0;                                   \
        _Pragma("unroll")                                                     \
        for (int J = 0; J < 4; ++J) {                     /* 4 uniform b128 */\
            const uint4 v_ = *reinterpret_cast<const uint4*>(wbuf + 4 * J);   \
            a0 = dot4(a0, eq[4 * J + 0], v_.x);                               \
            a1 = dot4(a1, eq[4 * J + 1], v_.y);                               \
            a2 = dot4(a2, eq[4 * J + 2], v_.z);                               \
            a3 = dot4(a3, eq[4 * J + 3], v_.w);                               \
        }                                                                     \
        const float cp_ = (float)((a0 + a1) + (a2 + a3)) * scl;               \
        RES = xt_ * ((ri + cp_) - xt_);                                       \
    } while (0)

// Per-iteration residency pin (R14-verified recipe).
#define PIN8(B)                                                               \
    asm volatile("" : "+v"(eq[B + 0]), "+v"(eq[B + 1]), "+v"(eq[B + 2]),      \
                      "+v"(eq[B + 3]), "+v"(eq[B + 4]), "+v"(eq[B + 5]),      \
                      "+v"(eq[B + 6]), "+v"(eq[B + 7]))

__global__ __launch_bounds__(WPB * 64)
__attribute__((amdgpu_waves_per_eu(2, 2)))
void glv_rk4_kernel(const float* __restrict__ x0,
                    const float* __restrict__ r,
                    const float* __restrict__ A,
                    const float* __restrict__ tgrid,
                    float* __restrict__ out)
{
    const int lane = threadIdx.x & 63;
    const int wid  = threadIdx.x >> 6;
    const int b    = blockIdx.x * WPB + wid;   // batch element for this wave

    // Per-wave broadcast buffer: 16 real dwords (64 x i8) + 48 shadow.
    __shared__ uint32_t xq[WPB][64];
    uint32_t* const wbuf = &xq[wid][0];
    const int waddr = (lane >> 2) + (lane & 3) * 16;  // shadow for lane%4 != 0

    // E = A + I, row `lane`, quantized i8 with per-row scale -> 16 VGPRs.
    float ev[D];
    float rowmax = 1e-30f;
#pragma unroll
    for (int j = 0; j < D; j += 4) {
        const float4 v = *reinterpret_cast<const float4*>(A + lane * D + j);
        ev[j + 0] = v.x + ((j + 0) == lane ? 1.0f : 0.0f);
        ev[j + 1] = v.y + ((j + 1) == lane ? 1.0f : 0.0f);
        ev[j + 2] = v.z + ((j + 2) == lane ? 1.0f : 0.0f);
        ev[j + 3] = v.w + ((j + 3) == lane ? 1.0f : 0.0f);
        rowmax = fmaxf(rowmax, fmaxf(fmaxf(fabsf(ev[j]), fabsf(ev[j + 1])),
                                     fmaxf(fabsf(ev[j + 2]), fabsf(ev[j + 3]))));
    }
    const float qinv = 127.0f / rowmax;
    const float scl  = rowmax * (1.0f / (127.0f * 127.0f));

    uint32_t eq[D / 4];
#pragma unroll
    for (int J = 0; J < D / 4; ++J) {
        const int b0 = (int)rintf(ev[4 * J + 0] * qinv);
        const int b1 = (int)rintf(ev[4 * J + 1] * qinv);
        const int b2 = (int)rintf(ev[4 * J + 2] * qinv);
        const int b3 = (int)rintf(ev[4 * J + 3] * qinv);
        eq[J] = (uint32_t)(b0 & 0xFF) | ((uint32_t)(b1 & 0xFF) << 8) |
                ((uint32_t)(b2 & 0xFF) << 16) | ((uint32_t)(b3 & 0xFF) << 24);
    }

    const float ri = r[lane];
    const float dt = tgrid[1] - tgrid[0];
    const float h2 = 0.5f * dt;
    const float h6 = dt * (1.0f / 6.0f);

    float x = x0[(size_t)b * D + lane];

    float* o = out + (size_t)b * NT * D + lane;
    *o = x; o += D;                            // t = 0 is x0

    for (int t = 1; t < NT; ++t) {
        PIN8(0); PIN8(8);                      // keep eq in arch VGPRs
        float k1, k2, k3, k4;
        FEVAL(x, k1);
        FEVAL(fmaf(h2, k1, x), k2);
        FEVAL(fmaf(h2, k2, x), k3);
        FEVAL(fmaf(dt, k3, x), k4);
        x = fmaf(h6, (k1 + k4) + 2.0f * (k2 + k3), x);
        *o = x; o += D;                        // coalesced 256 B/wave store
    }
}

extern "C" void kernel_launch(void* const* d_in, const int* in_sizes, int n_in,
                              void* d_out, int out_size, void* d_ws, size_t ws_size,
                              hipStream_t stream) {
    const float* x0    = (const float*)d_in[0];
    const float* r     = (const float*)d_in[1];
    const float* A     = (const float*)d_in[2];
    const float* tgrid = (const float*)d_in[3];
    float* out         = (float*)d_out;

    const int batch = in_sizes[0] / D;          // 2048
    dim3 grid(batch / WPB);                     // 512 blocks
    dim3 block(WPB * 64);                       // 256 threads = 4 waves

    glv_rk4_kernel<<<grid, block, 0, stream>>>(x0, r, A, tgrid, out);
}